// Round 9
// baseline (481.963 us; speedup 1.0000x reference)
//
#include <hip/hip_runtime.h>
#include <hip/hip_bf16.h>

#define N_NODES 100000
#define N_EDGES 600000
#define DIM     128
#define N_REL   8
#define N_GRAPH 64
#define N_LAYER 3
#define NR      (N_NODES * N_REL)   // 800000
#define NB1     782                 // ceil(NR / 1024)

typedef __attribute__((ext_vector_type(8))) short short8;
typedef __attribute__((ext_vector_type(4))) float float4v;

__device__ __forceinline__ float bflo(unsigned int u) {
    return __builtin_bit_cast(float, u << 16);
}
__device__ __forceinline__ float bfhi(unsigned int u) {
    return __builtin_bit_cast(float, u & 0xffff0000u);
}
__device__ __forceinline__ unsigned short f2bf(float f) {
    unsigned int u = __builtin_bit_cast(unsigned int, f);
    u += 0x7fffu + ((u >> 16) & 1u);          // RNE
    return (unsigned short)(u >> 16);
}
__device__ __forceinline__ unsigned int pack2(float a, float b) {
    return (unsigned int)f2bf(a) | ((unsigned int)f2bf(b) << 16);
}
// XOR-swizzle, 8-B granules, 128-B rows (fp8 tiles): 16 granules/row
__device__ __forceinline__ int gswz8(int row, int g) {
    return row * 16 + (g ^ (row & 15));
}
// XOR-swizzle, 16-B granules, 128-B rows (bf16 half tiles): 8 granules/row
__device__ __forceinline__ int gswzh(int row, int g) {
    return row * 8 + (g ^ (row & 7));
}
// XOR-swizzle, 16-B granules, 256-B rows (bf16 full tiles, fallback path)
__device__ __forceinline__ int gswz(int row, int g) {
    return row * 16 + (g ^ (row & 15));
}

// ---------------- utility: zero int buffer ----------------
__global__ void k_zero(int* __restrict__ p, int n) {
    int i = blockIdx.x * 256 + threadIdx.x;
    if (i < n) p[i] = 0;
}

// ---------------- counting sort of edges by seg = dst*8 + rel (dst-major) ----------------
__global__ void k_hist(const int* __restrict__ ei, const int* __restrict__ et,
                       int* __restrict__ counts) {
    int e = blockIdx.x * 256 + threadIdx.x;
    if (e < N_EDGES) {
        int seg = ei[N_EDGES + e] * N_REL + et[e];
        atomicAdd(&counts[seg], 1);
    }
}

__global__ __launch_bounds__(256) void k_scan1(const int* __restrict__ cnts,
                                               int* __restrict__ part,
                                               int* __restrict__ bsum) {
    __shared__ int sh[256];
    int t = threadIdx.x;
    int base = blockIdx.x * 1024 + t * 4;
    int v0 = (base + 0 < NR) ? cnts[base + 0] : 0;
    int v1 = (base + 1 < NR) ? cnts[base + 1] : 0;
    int v2 = (base + 2 < NR) ? cnts[base + 2] : 0;
    int v3 = (base + 3 < NR) ? cnts[base + 3] : 0;
    int tot = v0 + v1 + v2 + v3;
    sh[t] = tot;
    __syncthreads();
    for (int off = 1; off < 256; off <<= 1) {
        int x = (t >= off) ? sh[t - off] : 0;
        __syncthreads();
        sh[t] += x;
        __syncthreads();
    }
    int exc = sh[t] - tot;
    if (base + 0 < NR) part[base + 0] = exc;
    if (base + 1 < NR) part[base + 1] = exc + v0;
    if (base + 2 < NR) part[base + 2] = exc + v0 + v1;
    if (base + 3 < NR) part[base + 3] = exc + v0 + v1 + v2;
    if (t == 255) bsum[blockIdx.x] = sh[t];
}

__global__ __launch_bounds__(1024) void k_scan2(int* __restrict__ bsum, int nb) {
    __shared__ int sh[1024];
    int t = threadIdx.x;
    int v = (t < nb) ? bsum[t] : 0;
    sh[t] = v;
    __syncthreads();
    for (int off = 1; off < 1024; off <<= 1) {
        int x = (t >= off) ? sh[t - off] : 0;
        __syncthreads();
        sh[t] += x;
        __syncthreads();
    }
    if (t < nb) bsum[t] = sh[t] - v;   // exclusive block offsets
}

__global__ void k_scan3(const int* __restrict__ part, const int* __restrict__ bsum,
                        int* __restrict__ rowptr, int* __restrict__ cursor) {
    int i = blockIdx.x * 256 + threadIdx.x;
    if (i < NR) {
        int v = part[i] + bsum[i >> 10];
        rowptr[i] = v;
        cursor[i] = v;
    }
    if (i == 0) rowptr[NR] = N_EDGES;
}

__global__ void k_scatter(const int* __restrict__ ei, const int* __restrict__ et,
                          int* __restrict__ cursor, int* __restrict__ srcs) {
    int e = blockIdx.x * 256 + threadIdx.x;
    if (e < N_EDGES) {
        int seg = ei[N_EDGES + e] * N_REL + et[e];
        int p = atomicAdd(&cursor[seg], 1);
        srcs[p] = ei[e];
    }
}

// ---------------- x0 = node_emb[node_type], stored bf16x2 ----------------
__global__ void k_gather(const int* __restrict__ nt, const float* __restrict__ emb,
                         unsigned int* __restrict__ x2) {
    int gid = blockIdx.x * 256 + threadIdx.x;
    if (gid < N_NODES * 64) {
        int n = gid >> 6, c2 = gid & 63;
        const float* row = emb + (size_t)nt[n] * DIM + c2 * 2;
        x2[gid] = pack2(row[0], row[1]);
    }
}

// ---------------- weight prep: bf16 WT (root uses chunk 8) ----------------
__global__ void k_wprep(const float* __restrict__ relw, const float* __restrict__ rootw,
                        unsigned short* __restrict__ WT) {
    int gid = blockIdx.x * 256 + threadIdx.x;
    if (gid < N_LAYER * 9 * 16384) {
        int l = gid / (9 * 16384);
        int rem = gid - l * 9 * 16384;
        int c = rem >> 14;
        int idx = rem & 16383;
        int n = idx >> 7, k = idx & 127;
        float w = (c < 8) ? relw[(((size_t)l * 8 + c) * 128 + k) * 128 + n]
                          : rootw[((size_t)l * 128 + k) * 128 + n];
        WT[gid] = f2bf(w);
    }
}

// ---------------- weight prep: fp8 e4m3 rel planes, [l][r][n][k] ----------------
__global__ void k_wprep8(const float* __restrict__ relw, unsigned short* __restrict__ W8) {
    int gid = blockIdx.x * 256 + threadIdx.x;      // over L*8*128n*64kpair
    if (gid < N_LAYER * 8 * 8192) {
        int l = gid / (8 * 8192);
        int rem = gid - l * 8 * 8192;
        int r = rem >> 13;
        int idx = rem & 8191;
        int n = idx >> 6, kp = idx & 63;
        const float* base = relw + (((size_t)(l * 8 + r) * 128) * 128) + n;
        float w0 = base[(size_t)(2 * kp) * 128];
        float w1 = base[(size_t)(2 * kp + 1) * 128];
        int pk = __builtin_amdgcn_cvt_pk_fp8_f32(w0, w1, 0, false);
        W8[gid] = (unsigned short)(pk & 0xffff);
    }
}

// ---------------- per-dst aggregation: 4 nodes per wave, fp8 out, unroll-2 ----------------
// Quarter q (16 lanes) owns node 4w+q; lane j covers cols 8j..8j+7.
__global__ __launch_bounds__(256) void k_agg(
    const unsigned int* __restrict__ xin,   // [N][64] bf16x2
    const int* __restrict__ rowptr,         // [NR+1], seg = dst*8 + rel
    const int* __restrict__ srcs,           // [E] sorted by seg
    unsigned int* __restrict__ Ag8,         // [8][srows][32] fp8x4
    int d0, int rows, int srows)
{
    const int t = threadIdx.x;
    const int wv = t >> 6, lane = t & 63;
    const int q = lane >> 4, j = lane & 15;
    const int nb0 = (blockIdx.x * 4 + wv) * 4;     // first local node of this wave
    if (nb0 >= rows) return;
    const int myn = nb0 + q;
    const bool nvalid = (myn < rows);

    // preload rowptr[(d0+nb0)*8 + lane] for lane<33 (clamped)
    int pr = 0;
    {
        int idx = (d0 + nb0) * 8 + lane;
        if (idx > NR) idx = NR;
        if (lane < 33) pr = rowptr[idx];
    }
    const int P0 = __shfl(pr, 0);
    const int Dtot = __shfl(pr, 32) - P0;

    // lane l holds srcs[P0+l] (first 64 edges of the 4 nodes, contiguous)
    int my_src = 0;
    if (lane < Dtot) my_src = srcs[P0 + lane];

    const uint4* x4 = (const uint4*)xin;           // row = 16 uint4

    for (int r = 0; r < 8; ++r) {
        int e0 = __shfl(pr, q * 8 + r);
        int e1 = __shfl(pr, q * 8 + r + 1);
        int cnt = e1 - e0;                         // quarter-uniform
        int m1 = max(cnt, __shfl_xor(cnt, 16));
        int maxc = max(m1, __shfl_xor(m1, 32));    // wave max
        float a0 = 0.f, a1 = 0.f, a2 = 0.f, a3 = 0.f;
        float a4 = 0.f, a5 = 0.f, a6 = 0.f, a7 = 0.f;
        int k = 0;
        for (; k + 2 <= maxc; k += 2) {
            int ei0 = e0 + k, ei1 = e0 + k + 1;
            int r0 = ei0 - P0, r1 = ei1 - P0;
            int s0 = __shfl(my_src, r0 & 63);
            int s1 = __shfl(my_src, r1 & 63);
            if (r0 >= 64) s0 = srcs[ei0];          // essentially never
            if (r1 >= 64) s1 = srcs[ei1];
            bool v0 = (k < cnt), v1 = (k + 1 < cnt);
            uint4 u0, u1;
            if (v0) u0 = x4[(size_t)s0 * 16 + j];
            if (v1) u1 = x4[(size_t)s1 * 16 + j];
            if (v0) {
                a0 += bflo(u0.x); a1 += bfhi(u0.x);
                a2 += bflo(u0.y); a3 += bfhi(u0.y);
                a4 += bflo(u0.z); a5 += bfhi(u0.z);
                a6 += bflo(u0.w); a7 += bfhi(u0.w);
            }
            if (v1) {
                a0 += bflo(u1.x); a1 += bfhi(u1.x);
                a2 += bflo(u1.y); a3 += bfhi(u1.y);
                a4 += bflo(u1.z); a5 += bfhi(u1.z);
                a6 += bflo(u1.w); a7 += bfhi(u1.w);
            }
        }
        if (k < maxc) {
            int ei = e0 + k;
            int ridx = ei - P0;
            int s = __shfl(my_src, ridx & 63);
            if (ridx >= 64) s = srcs[ei];
            if (k < cnt) {
                uint4 u = x4[(size_t)s * 16 + j];
                a0 += bflo(u.x); a1 += bfhi(u.x);
                a2 += bflo(u.y); a3 += bfhi(u.y);
                a4 += bflo(u.z); a5 += bfhi(u.z);
                a6 += bflo(u.w); a7 += bfhi(u.w);
            }
        }
        float inv = (cnt > 0) ? 1.0f / (float)cnt : 0.f;
        int u0 = __builtin_amdgcn_cvt_pk_fp8_f32(a0 * inv, a1 * inv, 0, false);
        u0 = __builtin_amdgcn_cvt_pk_fp8_f32(a2 * inv, a3 * inv, u0, true);
        int u1 = __builtin_amdgcn_cvt_pk_fp8_f32(a4 * inv, a5 * inv, 0, false);
        u1 = __builtin_amdgcn_cvt_pk_fp8_f32(a6 * inv, a7 * inv, u1, true);
        if (nvalid) {
            uint2 v; v.x = (unsigned int)u0; v.y = (unsigned int)u1;
            *(uint2*)&Ag8[((size_t)r * srows + myn) * 32 + j * 2] = v;
        }
    }
}

// ---------------- dense MFMA GEMM, BM=128, 32 KB LDS ----------------
// 8 fp8 chunks (A/B 16 KB each) + bf16 root as 2 K=64 halves (A/B 16 KB each).
#define BM 64
#define BM2 128
__global__ __launch_bounds__(256) void k_gemm(
    const unsigned int* __restrict__ Ag8,   // [8][srows][32] fp8x4
    const unsigned int* __restrict__ xin,   // [N][64] bf16x2 (root chunk)
    unsigned int* __restrict__ xout,        // [N][64] bf16x2
    const unsigned short* __restrict__ W8,  // [8][128n][64kp] fp8 pairs (this layer)
    const unsigned short* __restrict__ WT,  // [9][128n][128k] bf16 (this layer; root = chunk 8)
    const float* __restrict__ bias,         // [128]
    int d0, int srows)
{
    __shared__ __align__(16) unsigned long long Als[2048];  // 16 KB A region
    __shared__ __align__(16) unsigned long long Bls[2048];  // 16 KB B region
    const int t = threadIdx.x;
    const int wv = t >> 6, lane = t & 63;
    const int quad = lane >> 4, l15 = lane & 15;
    const int m0 = d0 + blockIdx.x * BM2;

    float4v acc[2][8];
#pragma unroll
    for (int nt = 0; nt < 8; ++nt) {
        float bc = bias[nt * 16 + l15];
        acc[0][nt] = (float4v){bc, bc, bc, bc};
        acc[1][nt] = (float4v){bc, bc, bc, bc};
    }

    // ---- 8 fp8 chunks: A 128x128B, B 128x128B ----
    for (int c = 0; c < 8; ++c) {
        __syncthreads();
        {
            const unsigned long long* Wc = (const unsigned long long*)(W8 + (size_t)c * 8192);
#pragma unroll
            for (int i = 0; i < 8; ++i) {
                int idx = t + 256 * i;            // 0..2047 granules
                Bls[gswz8(idx >> 4, idx & 15)] = Wc[idx];
            }
        }
        {
            const unsigned long long* Ac = (const unsigned long long*)(Ag8 + ((size_t)c * srows + (m0 - d0)) * 32);
#pragma unroll
            for (int i = 0; i < 8; ++i) {
                int idx = t + 256 * i;
                Als[gswz8(idx >> 4, idx & 15)] = Ac[idx];
            }
        }
        __syncthreads();
#pragma unroll
        for (int kk = 0; kk < 4; ++kk) {
            int g = kk * 4 + quad;
            long long a0 = (long long)Als[(wv * 32 + l15) * 16 + (g ^ l15)];
            long long a1 = (long long)Als[(wv * 32 + 16 + l15) * 16 + (g ^ l15)];
#pragma unroll
            for (int nt = 0; nt < 8; ++nt) {
                long long b8 = (long long)Bls[(nt * 16 + l15) * 16 + (g ^ l15)];
                acc[0][nt] = __builtin_amdgcn_mfma_f32_16x16x32_fp8_fp8(a0, b8, acc[0][nt], 0, 0, 0);
                acc[1][nt] = __builtin_amdgcn_mfma_f32_16x16x32_fp8_fp8(a1, b8, acc[1][nt], 0, 0, 0);
            }
        }
    }
    // ---- root chunk (bf16), two K=64 halves; A/B half-tiles are 16 KB each ----
    for (int h = 0; h < 2; ++h) {
        __syncthreads();
        {
            uint4* A4 = (uint4*)Als;
            uint4* B4 = (uint4*)Bls;
            const uint4* Wc = (const uint4*)(WT + 8 * 16384);   // [128n][16 uint4]
            const uint4* Ac = (const uint4*)(xin + (size_t)m0 * 64);  // [128 rows][16 uint4]
#pragma unroll
            for (int i = 0; i < 4; ++i) {
                int idx = t + 256 * i;            // 0..1023: row = idx>>3, g = idx&7
                int row = idx >> 3, g = idx & 7;
                B4[gswzh(row, g)] = Wc[row * 16 + h * 8 + g];
                A4[gswzh(row, g)] = Ac[row * 16 + h * 8 + g];
            }
        }
        __syncthreads();
        {
            const unsigned short* Abfs = (const unsigned short*)Als;
            const unsigned short* Bbfs = (const unsigned short*)Bls;
#pragma unroll
            for (int kk = 0; kk < 2; ++kk) {
                int g = kk * 4 + quad;
                short8 a0 = *(const short8*)(Abfs + gswzh(wv * 32 + l15, g) * 8);
                short8 a1 = *(const short8*)(Abfs + gswzh(wv * 32 + 16 + l15, g) * 8);
#pragma unroll
                for (int nt = 0; nt < 8; ++nt) {
                    short8 b = *(const short8*)(Bbfs + gswzh(nt * 16 + l15, g) * 8);
                    acc[0][nt] = __builtin_amdgcn_mfma_f32_16x16x32_bf16(a0, b, acc[0][nt], 0, 0, 0);
                    acc[1][nt] = __builtin_amdgcn_mfma_f32_16x16x32_bf16(a1, b, acc[1][nt], 0, 0, 0);
                }
            }
        }
    }
    // ---- epilogue: relu, store bf16 ----
    unsigned short* outs = (unsigned short*)xout;
#pragma unroll
    for (int rt = 0; rt < 2; ++rt) {
#pragma unroll
        for (int nt = 0; nt < 8; ++nt) {
            int colg = nt * 16 + l15;
#pragma unroll
            for (int i = 0; i < 4; ++i) {
                int row = m0 + wv * 32 + rt * 16 + quad * 4 + i;
                if (row < N_NODES) {
                    float v = acc[rt][nt][i];
                    v = v > 0.f ? v : 0.f;
                    outs[(size_t)row * 128 + colg] = f2bf(v);
                }
            }
        }
    }
}

// ---------------- FALLBACK (fused layer; used only if ws too small) ----------------
__global__ __launch_bounds__(256) void k_layer_fb(
    const unsigned int* __restrict__ xin, unsigned int* __restrict__ xout,
    const int* __restrict__ rowptr, const int* __restrict__ srcs,
    const unsigned short* __restrict__ WT, const float* __restrict__ bias)
{
    __shared__ __align__(16) unsigned int Als[BM * 68];
    __shared__ __align__(16) unsigned int Bls[128 * 68];
    const int t = threadIdx.x;
    const int wv = t >> 6, lane = t & 63;
    const int quad = lane >> 4, l15 = lane & 15;
    const int m0 = blockIdx.x * BM;
    const int col2 = t & 63;
    const int rq = t >> 6;

    float4v acc[8];
#pragma unroll
    for (int nt = 0; nt < 8; ++nt) {
        float bc = bias[nt * 16 + l15];
        acc[nt] = (float4v){bc, bc, bc, bc};
    }
    for (int c = 0; c < 9; ++c) {
        if (c < 8) {
            for (int i = 0; i < 16; ++i) {
                int ml = rq + 4 * i;
                int m = m0 + ml;
                float a0 = 0.f, a1 = 0.f, inv = 0.f;
                if (m < N_NODES) {
                    int seg = m * N_REL + c;
                    int s = rowptr[seg], e = rowptr[seg + 1];
                    if (e > s) inv = 1.0f / (float)(e - s);
                    for (int jj = s; jj < e; ++jj) {
                        unsigned int u = xin[(size_t)srcs[jj] * 64 + col2];
                        a0 += bflo(u);
                        a1 += bfhi(u);
                    }
                }
                Als[ml * 68 + col2] = pack2(a0 * inv, a1 * inv);
            }
        } else {
            for (int i = 0; i < 16; ++i) {
                int ml = rq + 4 * i;
                int m = m0 + ml;
                Als[ml * 68 + col2] = (m < N_NODES) ? xin[(size_t)m * 64 + col2] : 0u;
            }
        }
        {
            const unsigned int* Wc = (const unsigned int*)(WT + c * 16384);
#pragma unroll
            for (int i = 0; i < 32; ++i) {
                int idx = t + 256 * i;
                Bls[(idx >> 6) * 68 + (idx & 63)] = Wc[idx];
            }
        }
        __syncthreads();
        const short* As = (const short*)Als;
        const short* Bs = (const short*)Bls;
#pragma unroll
        for (int kk = 0; kk < 4; ++kk) {
            short8 a = *(const short8*)(As + (wv * 16 + l15) * 136 + kk * 32 + quad * 8);
#pragma unroll
            for (int nt = 0; nt < 8; ++nt) {
                short8 b = *(const short8*)(Bs + (nt * 16 + l15) * 136 + kk * 32 + quad * 8);
                acc[nt] = __builtin_amdgcn_mfma_f32_16x16x32_bf16(a, b, acc[nt], 0, 0, 0);
            }
        }
        __syncthreads();
    }
    unsigned short* outs = (unsigned short*)xout;
#pragma unroll
    for (int nt = 0; nt < 8; ++nt) {
        int colg = nt * 16 + l15;
#pragma unroll
        for (int i = 0; i < 4; ++i) {
            int row = m0 + wv * 16 + quad * 4 + i;
            if (row < N_NODES) {
                float v = acc[nt][i];
                v = v > 0.f ? v : 0.f;
                outs[(size_t)row * 128 + colg] = f2bf(v);
            }
        }
    }
}

// ---------------- global mean pool (batch sorted): 64 nodes per wave ----------------
__global__ __launch_bounds__(256) void k_pool(const unsigned int* __restrict__ x2,
                                              const int* __restrict__ batch,
                                              float* __restrict__ gsum,
                                              int* __restrict__ gcnt) {
    const int wv = threadIdx.x >> 6, lane = threadIdx.x & 63;
    const int n0 = (blockIdx.x * 4 + wv) * 64;
    if (n0 >= N_NODES) return;
    int n1 = n0 + 64;
    if (n1 > N_NODES) n1 = N_NODES;
    const int nb = n1 - n0;
    int bb = batch[n0 + (lane < nb ? lane : nb - 1)];
    float a0 = 0.f, a1 = 0.f;
    int run = 0;
    int cur = __shfl(bb, 0);
    for (int base = 0; base < nb; base += 8) {
        unsigned int u[8];
        int m = nb - base;
#pragma unroll
        for (int qq = 0; qq < 8; ++qq)
            if (qq < m) u[qq] = x2[(size_t)(n0 + base + qq) * 64 + lane];
#pragma unroll
        for (int qq = 0; qq < 8; ++qq) {
            if (qq < m) {
                int b = __shfl(bb, base + qq);
                if (b != cur) {
                    atomicAdd(&gsum[cur * 128 + lane * 2], a0);
                    atomicAdd(&gsum[cur * 128 + lane * 2 + 1], a1);
                    if (lane == 0) atomicAdd(&gcnt[cur], run);
                    a0 = a1 = 0.f;
                    run = 0;
                    cur = b;
                }
                a0 += bflo(u[qq]);
                a1 += bfhi(u[qq]);
                ++run;
            }
        }
    }
    atomicAdd(&gsum[cur * 128 + lane * 2], a0);
    atomicAdd(&gsum[cur * 128 + lane * 2 + 1], a1);
    if (lane == 0) atomicAdd(&gcnt[cur], run);
}

// ---------------- MLP heads (fp32) ----------------
__global__ __launch_bounds__(128) void k_heads(
    const float* __restrict__ gsum, const int* __restrict__ gcnt,
    const float* __restrict__ rw1, const float* __restrict__ rb1,
    const float* __restrict__ rw2, const float* __restrict__ rb2,
    const float* __restrict__ sw1, const float* __restrict__ sb1,
    const float* __restrict__ sw2, const float* __restrict__ sb2,
    float* __restrict__ out) {
    __shared__ float g[128];
    __shared__ float parts[2];
    int b = blockIdx.x, t = threadIdx.x;
    int c = gcnt[b];
    float invc = 1.0f / (float)(c > 0 ? c : 1);
    g[t] = gsum[b * 128 + t] * invc;
    __syncthreads();
    float acc = rb1[t];
    for (int d = 0; d < 128; ++d) acc += g[d] * rw1[d * 128 + t];
    float h = acc > 0.f ? acc : 0.f;
    float p = h * rw2[t];
    for (int o = 32; o > 0; o >>= 1) p += __shfl_down(p, o);
    if ((t & 63) == 0) parts[t >> 6] = p;
    __syncthreads();
    if (t == 0) out[b] = parts[0] + parts[1] + rb2[0];
    __syncthreads();
    acc = sb1[t];
    for (int d = 0; d < 128; ++d) acc += g[d] * sw1[d * 128 + t];
    h = acc > 0.f ? acc : 0.f;
    p = h * sw2[t];
    for (int o = 32; o > 0; o >>= 1) p += __shfl_down(p, o);
    if ((t & 63) == 0) parts[t >> 6] = p;
    __syncthreads();
    if (t == 0) out[64 + b] = parts[0] + parts[1] + sb2[0];
}

extern "C" void kernel_launch(void* const* d_in, const int* in_sizes, int n_in,
                              void* d_out, int out_size, void* d_ws, size_t ws_size,
                              hipStream_t stream) {
    const int*   node_type  = (const int*)d_in[0];
    const int*   edge_index = (const int*)d_in[1];
    const int*   edge_type  = (const int*)d_in[2];
    const int*   batch      = (const int*)d_in[3];
    const float* node_emb   = (const float*)d_in[4];
    const float* rel_w      = (const float*)d_in[5];
    const float* root_w     = (const float*)d_in[6];
    const float* bias       = (const float*)d_in[7];
    const float* rw1        = (const float*)d_in[8];
    const float* rb1        = (const float*)d_in[9];
    const float* rw2        = (const float*)d_in[10];
    const float* rb2        = (const float*)d_in[11];
    const float* sw1        = (const float*)d_in[12];
    const float* sb1        = (const float*)d_in[13];
    const float* sw2        = (const float*)d_in[14];
    const float* sb2        = (const float*)d_in[15];
    float* out = (float*)d_out;

    char* ws = (char*)d_ws;
    size_t off = 0;
    auto alloc = [&](size_t bytes) -> void* {
        void* p = ws + off;
        off += (bytes + 255) & ~(size_t)255;
        return p;
    };
    // ---- persistent region ----
    unsigned int*   xa     = (unsigned int*)alloc((size_t)N_NODES * 64 * 4);
    unsigned int*   xb     = (unsigned int*)alloc((size_t)N_NODES * 64 * 4);
    int*            rowptr = (int*)alloc((size_t)(NR + 1) * 4);
    int*            srcs   = (int*)alloc((size_t)N_EDGES * 4);
    int*            bsum   = (int*)alloc(1024 * 4);
    unsigned short* WT     = (unsigned short*)alloc((size_t)N_LAYER * 9 * 16384 * 2);
    unsigned short* W8     = (unsigned short*)alloc((size_t)N_LAYER * 8 * 8192 * 2);
    float*          gsum   = (float*)alloc((64 * 128 + 64) * 4);
    int*            gcnt   = (int*)(gsum + 64 * 128);
    size_t off_common = off;
    // ---- scratch region: sort temps, later overlapped by Ag8 slices ----
    int*            cursor = (int*)alloc((size_t)NR * 4);
    int*            counts = (int*)alloc((size_t)NR * 4);
    size_t off_sort = off;
    if (off_sort > ws_size) return;                // cannot run at all
    unsigned int*   Ag8    = (unsigned int*)(ws + off_common);  // overlaps cursor/counts
    size_t avail = ws_size - off_common;
    long max_rows = (avail > 32768) ? (long)((avail - 32768) / 1024) : 0;  // 32 KB tail-read slack
    int srows = (int)((max_rows / 64) * 64);
    if (srows > N_NODES + 63) srows = ((N_NODES + 63) / 64) * 64;
    const bool split_ok = (srows >= 128);

    // edge sort (counting sort by dst*8 + rel)
    k_zero<<<(NR + 255) / 256, 256, 0, stream>>>(counts, NR);
    k_zero<<<(64 * 128 + 64 + 255) / 256, 256, 0, stream>>>((int*)gsum, 64 * 128 + 64);
    k_hist<<<(N_EDGES + 255) / 256, 256, 0, stream>>>(edge_index, edge_type, counts);
    k_scan1<<<NB1, 256, 0, stream>>>(counts, cursor, bsum);
    k_scan2<<<1, 1024, 0, stream>>>(bsum, NB1);
    k_scan3<<<(NR + 255) / 256, 256, 0, stream>>>(cursor, bsum, rowptr, cursor);
    k_scatter<<<(N_EDGES + 255) / 256, 256, 0, stream>>>(edge_index, edge_type, cursor, srcs);

    // x0 gather + weight prep (bf16 + fp8)
    k_gather<<<(N_NODES * 64 + 255) / 256, 256, 0, stream>>>(node_type, node_emb, xa);
    k_wprep<<<(N_LAYER * 9 * 16384 + 255) / 256, 256, 0, stream>>>(rel_w, root_w, WT);
    k_wprep8<<<(N_LAYER * 8 * 8192 + 255) / 256, 256, 0, stream>>>(rel_w, W8);

    const int mblocks = (N_NODES + BM - 1) / BM;   // 1563 (fallback)
    unsigned int* xcur = xa;
    unsigned int* xnext = xb;
    for (int l = 0; l < N_LAYER; ++l) {
        const unsigned short* Wl  = WT + (size_t)l * 9 * 16384;
        const unsigned short* W8l = W8 + (size_t)l * 8 * 8192;
        const float* bl = bias + (size_t)l * 128;
        if (split_ok) {
            for (int d0 = 0; d0 < N_NODES; d0 += srows) {
                int rows = N_NODES - d0;
                if (rows > srows) rows = srows;
                int ab = (rows + 15) / 16;                 // 16 nodes per block (4 waves x 4)
                int gb = (rows + BM2 - 1) / BM2;
                k_agg<<<ab, 256, 0, stream>>>(xcur, rowptr, srcs, Ag8, d0, rows, srows);
                k_gemm<<<gb, 256, 0, stream>>>(Ag8, xcur, xnext, W8l, Wl, bl, d0, srows);
            }
        } else {
            k_layer_fb<<<mblocks, 256, 0, stream>>>(xcur, xnext, rowptr, srcs, Wl, bl);
        }
        unsigned int* tmp = xcur; xcur = xnext; xnext = tmp;
    }

    // pool + heads (final activations are in xcur after swap)
    k_pool<<<(N_NODES + 255) / 256, 256, 0, stream>>>(xcur, batch, gsum, gcnt);
    k_heads<<<64, 128, 0, stream>>>(gsum, gcnt, rw1, rb1, rw2, rb2,
                                    sw1, sb1, sw2, sb2, out);
}